// Round 1
// baseline (265.909 us; speedup 1.0000x reference)
//
#include <hip/hip_runtime.h>
#include <stdint.h>

// Problem constants (B=2, T=1024 -> N=2048 tokens; D=H=1024; E=8; top-2)
#define D_DIM 1024
#define H_DIM 1024
#define NE 8
#define NTOK 2048
#define SHARED_BASE 5120   // expert padded slots fit in [0,5120); shared rows follow
#define TOTAL_ROWS 7168    // 5120 + 2048
#define MAX_MSLOTS 56      // max expert tiles (<=39) + 16 shared tiles

typedef __bf16 bf16;
typedef bf16 bf16x8 __attribute__((ext_vector_type(8)));
typedef float f32x4 __attribute__((ext_vector_type(4)));

// ---- workspace layout (bytes); total needed ~71.4 MB ----
#define WS_CNT        0           // 8 ints (+pad, memset 64B)
#define WS_NTILES     64          // 1 int
#define WS_OFFS       128         // 8 ints
#define WS_TILE_E     256         // 64 ints
#define WS_TILE_BASE  512         // 64 ints
#define WS_TILE_VALID 768         // 64 ints
#define WS_EIDX       1024        // 4096 ints
#define WS_POS        17408       // 4096 ints
#define WS_WTOK       33792       // 4096 floats
#define WS_TOK        65536       // 7168 ints
#define WS_WGTS       98304       // 7168 floats
#define WS_XG         131072      // 7168*1024 bf16 = 14,680,064 B
#define WS_HID        16777216    // 7168*1024 bf16
#define WS_W1B        33554432    // 8M bf16 = 16 MB
#define WS_W2B        50331648    // 16 MB
#define WS_CFCB       67108864    // 2 MB
#define WS_CPROJB     69206016    // 2 MB (end 71,303,168)

typedef __attribute__((address_space(1))) void as1_void;
typedef __attribute__((address_space(3))) void as3_void;

__device__ __forceinline__ void async_ld16(const bf16* g, bf16* l) {
  __builtin_amdgcn_global_load_lds((as1_void*)(void*)g, (as3_void*)l, 16, 0, 0);
}

// ---- fp32 -> bf16 bulk convert (n divisible by 2048) ----
__global__ __launch_bounds__(256) void convf2b(const float* __restrict__ s,
                                               bf16* __restrict__ d, int n) {
  int i = (blockIdx.x * 256 + threadIdx.x) * 8;
  if (i >= n) return;
  float4 a = *(const float4*)(s + i);
  float4 b = *(const float4*)(s + i + 4);
  union { uint4 v; bf16 h[8]; } t;
  t.h[0] = (bf16)a.x; t.h[1] = (bf16)a.y; t.h[2] = (bf16)a.z; t.h[3] = (bf16)a.w;
  t.h[4] = (bf16)b.x; t.h[5] = (bf16)b.y; t.h[6] = (bf16)b.z; t.h[7] = (bf16)b.w;
  *(uint4*)(d + i) = t.v;
}

// ---- router: logits, top-2 (bias added for selection only), sigmoid weights,
//      per-expert counts/positions; also converts x rows to bf16 into the
//      shared-expert region of xg. One wave per token. ----
__global__ __launch_bounds__(256) void router_kernel(
    const float* __restrict__ x, const float* __restrict__ gw,
    const float* __restrict__ lb, int* __restrict__ cnt, int* __restrict__ eidx,
    int* __restrict__ posA, float* __restrict__ wtok, int* __restrict__ tok,
    float* __restrict__ wgts, bf16* __restrict__ xg) {
  const int wave = threadIdx.x >> 6;
  const int lane = threadIdx.x & 63;
  const int n = blockIdx.x * 4 + wave;

  const float4* xr = (const float4*)(x + (size_t)n * D_DIM);
  float4 xv[4];
#pragma unroll
  for (int q = 0; q < 4; q++) xv[q] = xr[q * 64 + lane];

  float acc[NE];
#pragma unroll
  for (int e = 0; e < NE; e++) acc[e] = 0.f;
#pragma unroll
  for (int e = 0; e < NE; e++) {
    const float4* gr = (const float4*)(gw + e * D_DIM);
#pragma unroll
    for (int q = 0; q < 4; q++) {
      float4 g = gr[q * 64 + lane];
      acc[e] += xv[q].x * g.x + xv[q].y * g.y + xv[q].z * g.z + xv[q].w * g.w;
    }
  }

  // bf16 x row into shared region
  bf16* dst = xg + (size_t)(SHARED_BASE + n) * D_DIM;
#pragma unroll
  for (int q = 0; q < 4; q++) {
    union { ushort4 u; bf16 h[4]; } t;
    t.h[0] = (bf16)xv[q].x; t.h[1] = (bf16)xv[q].y;
    t.h[2] = (bf16)xv[q].z; t.h[3] = (bf16)xv[q].w;
    *(ushort4*)(dst + (q * 64 + lane) * 4) = t.u;
  }

#pragma unroll
  for (int e = 0; e < NE; e++)
#pragma unroll
    for (int off = 32; off > 0; off >>= 1) acc[e] += __shfl_xor(acc[e], off, 64);

  if (lane == 0) {
    float b[NE];
#pragma unroll
    for (int e = 0; e < NE; e++) b[e] = acc[e] + lb[e];
    int i0 = 0; float v0 = b[0];
#pragma unroll
    for (int e = 1; e < NE; e++) if (b[e] > v0) { v0 = b[e]; i0 = e; }
    int i1 = -1; float v1 = -3.4e38f;
#pragma unroll
    for (int e = 0; e < NE; e++) if (e != i0 && b[e] > v1) { v1 = b[e]; i1 = e; }
    // gating uses UNbiased logits (take_along_axis on logits)
    float s0 = 1.f / (1.f + expf(-acc[i0]));
    float s1 = 1.f / (1.f + expf(-acc[i1]));
    float s = s0 + s1 + 1e-6f;
    float w0 = s0 / s, w1 = s1 / s;
    int p0 = atomicAdd(&cnt[i0], 1);
    int p1 = atomicAdd(&cnt[i1], 1);
    eidx[n * 2] = i0;     posA[n * 2] = p0;     wtok[n * 2] = w0;
    eidx[n * 2 + 1] = i1; posA[n * 2 + 1] = p1; wtok[n * 2 + 1] = w1;
    tok[SHARED_BASE + n] = n; wgts[SHARED_BASE + n] = 1.0f;
  }
}

// ---- tile table: padded per-expert slot ranges + appended shared tiles ----
__global__ void prefix_kernel(const int* __restrict__ cnt, int* __restrict__ offs,
                              int* __restrict__ tE, int* __restrict__ tB,
                              int* __restrict__ tV, int* __restrict__ ntiles) {
  if (threadIdx.x != 0 || blockIdx.x != 0) return;
  int nt = 0, base = 0;
  for (int e = 0; e < NE; e++) {
    offs[e] = base;
    int c = cnt[e];
    int t8 = (c + 127) >> 7;
    for (int t = 0; t < t8; t++) {
      tE[nt] = e; tB[nt] = base + t * 128;
      int v = c - t * 128; tV[nt] = v > 128 ? 128 : v; nt++;
    }
    base += t8 * 128;
  }
  for (int t = 0; t < 16; t++) {
    tE[nt] = NE; tB[nt] = SHARED_BASE + t * 128; tV[nt] = 128; nt++;
  }
  ntiles[0] = nt;
}

// ---- gather: copy bf16 x rows into per-expert slots; record token/weight ----
__global__ __launch_bounds__(256) void gather_kernel(
    const int* __restrict__ eidx, const int* __restrict__ posA,
    const float* __restrict__ wtok, const int* __restrict__ offs,
    int* __restrict__ tok, float* __restrict__ wgts, bf16* __restrict__ xg) {
  const int r = blockIdx.x;       // 0..4095 = (n,k)
  const int n = r >> 1;
  const int e = eidx[r];
  const int slot = offs[e] + posA[r];
  if (threadIdx.x == 0) { tok[slot] = n; wgts[slot] = wtok[r]; }
  const uint2* src = (const uint2*)(xg + (size_t)(SHARED_BASE + n) * D_DIM);
  uint2* dst = (uint2*)(xg + (size_t)slot * D_DIM);
  dst[threadIdx.x] = src[threadIdx.x];
}

// ---- table-driven 128x128 bf16 GEMM (C = A·B^T), m97 structure.
// MODE 0: relu^2 -> bf16 store to hid.  MODE 1: atomicAdd(wgt*acc) into out. ----
template <int MODE>
__global__ __launch_bounds__(256) void moe_gemm(
    const bf16* __restrict__ Ab, const bf16* __restrict__ We,
    const bf16* __restrict__ Ws, const int* __restrict__ tE,
    const int* __restrict__ tB, const int* __restrict__ tV,
    const int* __restrict__ ntp, bf16* __restrict__ hid,
    float* __restrict__ out, const int* __restrict__ tok,
    const float* __restrict__ wgts) {
  const int mslot = blockIdx.x;
  if (mslot >= ntp[0]) return;
  const int e = tE[mslot];
  const int base = tB[mslot];
  const bf16* Bp = (e < NE) ? (We + (size_t)e * (H_DIM * D_DIM)) : Ws;
  const int n0 = blockIdx.y * 128;

  __shared__ bf16 As[128 * 32];
  __shared__ bf16 Bs[128 * 32];

  const int tid = threadIdx.x;
  const int wave = tid >> 6, lane = tid & 63;

  // staging: chunk c -> row c/4, k-offset (c%4)*8; thread does c=tid, c=tid+256
  const int rS = tid >> 2;
  const int kc = (tid & 3) * 8;
  const bf16* gA0 = Ab + (size_t)(base + rS) * 1024 + kc;
  const bf16* gA1 = gA0 + (size_t)64 * 1024;
  const bf16* gB0 = Bp + (size_t)(n0 + rS) * 1024 + kc;
  const bf16* gB1 = gB0 + (size_t)64 * 1024;
  bf16* sA0 = As + tid * 8;           // byte offset tid*16
  bf16* sA1 = As + 2048 + tid * 8;
  bf16* sB0 = Bs + tid * 8;
  bf16* sB1 = Bs + 2048 + tid * 8;

  const int wm = (wave >> 1) * 64, wn = (wave & 1) * 64;
  const int fr = lane & 15, q8 = (lane >> 4) * 8;
  const bf16* aP[4];
  const bf16* bP[4];
#pragma unroll
  for (int i = 0; i < 4; i++) {
    aP[i] = As + (wm + i * 16 + fr) * 32 + q8;
    bP[i] = Bs + (wn + i * 16 + fr) * 32 + q8;
  }

  const f32x4 zero = {0.f, 0.f, 0.f, 0.f};
  f32x4 acc[4][4];
#pragma unroll
  for (int i = 0; i < 4; i++)
#pragma unroll
    for (int j = 0; j < 4; j++) acc[i][j] = zero;

  for (int kt = 0; kt < 32; ++kt) {
    const int ko = kt * 32;
    async_ld16(gA0 + ko, sA0);
    async_ld16(gA1 + ko, sA1);
    async_ld16(gB0 + ko, sB0);
    async_ld16(gB1 + ko, sB1);
    __syncthreads();  // compiler drains vmcnt before s_barrier -> LDS ready
    bf16x8 af[4], bfv[4];
#pragma unroll
    for (int i = 0; i < 4; i++) af[i] = *(const bf16x8*)aP[i];
#pragma unroll
    for (int j = 0; j < 4; j++) bfv[j] = *(const bf16x8*)bP[j];
#pragma unroll
    for (int i = 0; i < 4; i++)
#pragma unroll
      for (int j = 0; j < 4; j++)
        acc[i][j] = __builtin_amdgcn_mfma_f32_16x16x32_bf16(af[i], bfv[j],
                                                            acc[i][j], 0, 0, 0);
    __syncthreads();
  }

  const int rbase = (lane >> 4) * 4;
  if (MODE == 0) {
#pragma unroll
    for (int i = 0; i < 4; i++) {
#pragma unroll
      for (int j = 0; j < 4; j++) {
        const int col = n0 + wn + j * 16 + fr;
#pragma unroll
        for (int r = 0; r < 4; r++) {
          const int row = wm + i * 16 + rbase + r;
          float v = acc[i][j][r];
          v = v > 0.f ? v * v : 0.f;
          hid[(size_t)(base + row) * 1024 + col] = (bf16)v;
        }
      }
    }
  } else {
    const int valid = tV[mslot];
#pragma unroll
    for (int i = 0; i < 4; i++) {
#pragma unroll
      for (int r = 0; r < 4; r++) {
        const int row = wm + i * 16 + rbase + r;
        if (row < valid) {
          const int t = tok[base + row];
          const float wg = wgts[base + row];
          float* orow = out + (size_t)t * 1024 + n0 + wn + fr;
#pragma unroll
          for (int j = 0; j < 4; j++)
            atomicAdd(orow + j * 16, wg * acc[i][j][r]);
        }
      }
    }
  }
}

extern "C" void kernel_launch(void* const* d_in, const int* in_sizes, int n_in,
                              void* d_out, int out_size, void* d_ws,
                              size_t ws_size, hipStream_t stream) {
  const float* x     = (const float*)d_in[0];
  const float* gw    = (const float*)d_in[1];
  const float* lb    = (const float*)d_in[2];
  const float* w1    = (const float*)d_in[3];
  const float* w2    = (const float*)d_in[4];
  const float* cfc   = (const float*)d_in[5];
  const float* cproj = (const float*)d_in[6];
  float* out = (float*)d_out;
  char* ws = (char*)d_ws;

  int*   cnt   = (int*)(ws + WS_CNT);
  int*   ntl   = (int*)(ws + WS_NTILES);
  int*   offs  = (int*)(ws + WS_OFFS);
  int*   tE    = (int*)(ws + WS_TILE_E);
  int*   tB    = (int*)(ws + WS_TILE_BASE);
  int*   tV    = (int*)(ws + WS_TILE_VALID);
  int*   eidx  = (int*)(ws + WS_EIDX);
  int*   posA  = (int*)(ws + WS_POS);
  float* wtok  = (float*)(ws + WS_WTOK);
  int*   tok   = (int*)(ws + WS_TOK);
  float* wgts  = (float*)(ws + WS_WGTS);
  bf16*  xg    = (bf16*)(ws + WS_XG);
  bf16*  hid   = (bf16*)(ws + WS_HID);
  bf16*  w1b   = (bf16*)(ws + WS_W1B);
  bf16*  w2b   = (bf16*)(ws + WS_W2B);
  bf16*  cfcb  = (bf16*)(ws + WS_CFCB);
  bf16*  cprojb= (bf16*)(ws + WS_CPROJB);

  hipMemsetAsync(cnt, 0, 64, stream);
  hipMemsetAsync(out, 0, (size_t)out_size * sizeof(float), stream);

  convf2b<<<4096, 256, 0, stream>>>(w1, w1b, NE * H_DIM * D_DIM);
  convf2b<<<4096, 256, 0, stream>>>(w2, w2b, NE * D_DIM * H_DIM);
  convf2b<<<512, 256, 0, stream>>>(cfc, cfcb, H_DIM * D_DIM);
  convf2b<<<512, 256, 0, stream>>>(cproj, cprojb, D_DIM * H_DIM);

  router_kernel<<<NTOK / 4, 256, 0, stream>>>(x, gw, lb, cnt, eidx, posA, wtok,
                                              tok, wgts, xg);
  prefix_kernel<<<1, 1, 0, stream>>>(cnt, offs, tE, tB, tV, ntl);
  gather_kernel<<<NTOK * 2, 256, 0, stream>>>(eidx, posA, wtok, offs, tok, wgts,
                                              xg);

  moe_gemm<0><<<dim3(MAX_MSLOTS, 8), 256, 0, stream>>>(
      xg, w1b, cfcb, tE, tB, tV, ntl, hid, nullptr, nullptr, nullptr);
  moe_gemm<1><<<dim3(MAX_MSLOTS, 8), 256, 0, stream>>>(
      hid, w2b, cprojb, tE, tB, tV, ntl, nullptr, out, tok, wgts);
}

// Round 2
// 226.846 us; speedup vs baseline: 1.1722x; 1.1722x over previous
//
#include <hip/hip_runtime.h>
#include <stdint.h>

// Problem constants (B=2, T=1024 -> N=2048 tokens; D=H=1024; E=8; top-2)
#define D_DIM 1024
#define H_DIM 1024
#define NE 8
#define NTOK 2048
#define SHARED_BASE 5120   // expert padded slots fit in [0,5120); shared rows follow
#define TOTAL_ROWS 7168    // 5120 + 2048
#define MAX_MSLOTS 56      // max expert tiles (<=40) + 16 shared tiles

typedef __bf16 bf16;
typedef bf16 bf16x8 __attribute__((ext_vector_type(8)));
typedef float f32x4 __attribute__((ext_vector_type(4)));

// ---- workspace layout (bytes) ----
#define WS_NTILES     64          // 1 int
#define WS_TILE_E     256         // 64 ints
#define WS_TILE_BASE  512         // 64 ints
#define WS_TILE_VALID 768         // 64 ints
#define WS_EIDX       1024        // 4096 ints
#define WS_WTOK       33792       // 4096 floats
#define WS_TOK        65536       // 7168 ints
#define WS_WGTS       98304       // 7168 floats
#define WS_XG         131072      // 7168*1024 bf16 (only shared region used)
#define WS_HID        16777216    // 7168*1024 bf16
#define WS_W1B        33554432    // 16 MB
#define WS_W2B        50331648    // 16 MB
#define WS_CFCB       67108864    // 2 MB
#define WS_CPROJB     69206016    // 2 MB (end 71,303,168)

typedef __attribute__((address_space(1))) void as1_void;
typedef __attribute__((address_space(3))) void as3_void;

__device__ __forceinline__ void async_ld16(const bf16* g, bf16* l) {
  __builtin_amdgcn_global_load_lds((as1_void*)(void*)g, (as3_void*)l, 16, 0, 0);
}

// ---- fp32 -> bf16 bulk convert ----
__global__ __launch_bounds__(256) void convf2b(const float* __restrict__ s,
                                               bf16* __restrict__ d, int n) {
  int i = (blockIdx.x * 256 + threadIdx.x) * 8;
  if (i >= n) return;
  float4 a = *(const float4*)(s + i);
  float4 b = *(const float4*)(s + i + 4);
  union { uint4 v; bf16 h[8]; } t;
  t.h[0] = (bf16)a.x; t.h[1] = (bf16)a.y; t.h[2] = (bf16)a.z; t.h[3] = (bf16)a.w;
  t.h[4] = (bf16)b.x; t.h[5] = (bf16)b.y; t.h[6] = (bf16)b.z; t.h[7] = (bf16)b.w;
  *(uint4*)(d + i) = t.v;
}

// ---- router: logits, top-2 (bias for selection only), sigmoid weights.
//      NO atomics. Also converts x rows to bf16 (shared-token region). ----
__global__ __launch_bounds__(256) void router_kernel(
    const float* __restrict__ x, const float* __restrict__ gw,
    const float* __restrict__ lb, int* __restrict__ eidx,
    float* __restrict__ wtok, bf16* __restrict__ xg) {
  const int wave = threadIdx.x >> 6;
  const int lane = threadIdx.x & 63;
  const int n = blockIdx.x * 4 + wave;

  const float4* xr = (const float4*)(x + (size_t)n * D_DIM);
  float4 xv[4];
#pragma unroll
  for (int q = 0; q < 4; q++) xv[q] = xr[q * 64 + lane];

  float acc[NE];
#pragma unroll
  for (int e = 0; e < NE; e++) acc[e] = 0.f;
#pragma unroll
  for (int e = 0; e < NE; e++) {
    const float4* gr = (const float4*)(gw + e * D_DIM);
#pragma unroll
    for (int q = 0; q < 4; q++) {
      float4 g = gr[q * 64 + lane];
      acc[e] += xv[q].x * g.x + xv[q].y * g.y + xv[q].z * g.z + xv[q].w * g.w;
    }
  }

  bf16* dst = xg + (size_t)n * D_DIM;
#pragma unroll
  for (int q = 0; q < 4; q++) {
    union { ushort4 u; bf16 h[4]; } t;
    t.h[0] = (bf16)xv[q].x; t.h[1] = (bf16)xv[q].y;
    t.h[2] = (bf16)xv[q].z; t.h[3] = (bf16)xv[q].w;
    *(ushort4*)(dst + (q * 64 + lane) * 4) = t.u;
  }

#pragma unroll
  for (int e = 0; e < NE; e++)
#pragma unroll
    for (int off = 32; off > 0; off >>= 1) acc[e] += __shfl_xor(acc[e], off, 64);

  if (lane == 0) {
    float b[NE];
#pragma unroll
    for (int e = 0; e < NE; e++) b[e] = acc[e] + lb[e];
    int i0 = 0; float v0 = b[0];
#pragma unroll
    for (int e = 1; e < NE; e++) if (b[e] > v0) { v0 = b[e]; i0 = e; }
    int i1 = -1; float v1 = -3.4e38f;
#pragma unroll
    for (int e = 0; e < NE; e++) if (e != i0 && b[e] > v1) { v1 = b[e]; i1 = e; }
    float s0 = 1.f / (1.f + expf(-acc[i0]));
    float s1 = 1.f / (1.f + expf(-acc[i1]));
    float s = s0 + s1 + 1e-6f;
    eidx[n * 2] = i0;     wtok[n * 2] = s0 / s;
    eidx[n * 2 + 1] = i1; wtok[n * 2 + 1] = s1 / s;
  }
}

// ---- assign: single block. Ballot-aggregated per-expert positions, tile
// table, tok/wgts tables (incl. padding + shared region). ----
__global__ __launch_bounds__(256) void assign_kernel(
    const int* __restrict__ eidx, const float* __restrict__ wtok,
    int* __restrict__ tE, int* __restrict__ tB, int* __restrict__ tV,
    int* __restrict__ ntiles, int* __restrict__ tok,
    float* __restrict__ wgts) {
  __shared__ int segCnt[64][NE];
  __shared__ int segBase[64][NE];
  const int tid = threadIdx.x;
  const int wave = tid >> 6, lane = tid & 63;
  const unsigned long long below = (lane == 0) ? 0ull : ((~0ull) >> (64 - lane));

  int e16[16], pr16[16];
#pragma unroll
  for (int t = 0; t < 16; t++) {
    const int r = t * 256 + tid;
    const int seg = t * 4 + wave;
    const int e = eidx[r];
    int prior = 0;
#pragma unroll
    for (int ee = 0; ee < NE; ee++) {
      unsigned long long m = __ballot(e == ee);
      if (e == ee) prior = __popcll(m & below);
      if (lane == ee) segCnt[seg][ee] = __popcll(m);
    }
    e16[t] = e; pr16[t] = prior;
  }

  // init tok/wgts: pads -> token 0 / weight 0; shared region -> identity
  for (int s = tid; s < TOTAL_ROWS; s += 256) {
    if (s < SHARED_BASE) { tok[s] = 0; wgts[s] = 0.f; }
    else { tok[s] = s - SHARED_BASE; wgts[s] = 1.f; }
  }
  __syncthreads();

  if (wave == 0) {
    int v[NE], inc[NE];
#pragma unroll
    for (int e = 0; e < NE; e++) { v[e] = segCnt[lane][e]; inc[e] = v[e]; }
#pragma unroll
    for (int off = 1; off < 64; off <<= 1) {
#pragma unroll
      for (int e = 0; e < NE; e++) {
        int u = __shfl_up(inc[e], off);
        if (lane >= off) inc[e] += u;
      }
    }
    int tot[NE];
#pragma unroll
    for (int e = 0; e < NE; e++) tot[e] = __shfl(inc[e], 63);
    int offsL[NE]; int b = 0;
#pragma unroll
    for (int e = 0; e < NE; e++) { offsL[e] = b; b += ((tot[e] + 127) >> 7) << 7; }
#pragma unroll
    for (int e = 0; e < NE; e++) segBase[lane][e] = offsL[e] + (inc[e] - v[e]);
    if (lane == 0) {
      int nt = 0;
      for (int e = 0; e < NE; e++) {
        int c = tot[e];
        int t8 = (c + 127) >> 7;
        for (int t = 0; t < t8; t++) {
          tE[nt] = e; tB[nt] = offsL[e] + t * 128;
          int vv = c - t * 128; tV[nt] = vv > 128 ? 128 : vv; nt++;
        }
      }
      for (int t = 0; t < 16; t++) {
        tE[nt] = NE; tB[nt] = SHARED_BASE + t * 128; tV[nt] = 128; nt++;
      }
      ntiles[0] = nt;
    }
  }
  __syncthreads();

#pragma unroll
  for (int t = 0; t < 16; t++) {
    const int r = t * 256 + tid;
    const int seg = t * 4 + wave;
    const int slot = segBase[seg][e16[t]] + pr16[t];
    tok[slot] = r >> 1;
    wgts[slot] = wtok[r];
  }
}

// ---- table-driven 128x128 bf16 GEMM (C = A·B^T), m97 structure.
// MODE 0: A gathered via tok[] from xg; relu^2 -> bf16 store to hid.
// MODE 1: A direct from hid; atomicAdd(wgt*acc) into out. ----
template <int MODE>
__global__ __launch_bounds__(256) void moe_gemm(
    const bf16* __restrict__ Ab, const bf16* __restrict__ We,
    const bf16* __restrict__ Ws, const int* __restrict__ tE,
    const int* __restrict__ tB, const int* __restrict__ tV,
    const int* __restrict__ ntp, bf16* __restrict__ hid,
    float* __restrict__ out, const int* __restrict__ tok,
    const float* __restrict__ wgts) {
  const int mslot = blockIdx.x;
  if (mslot >= ntp[0]) return;
  const int e = tE[mslot];
  const int base = tB[mslot];
  const bf16* Bp = (e < NE) ? (We + (size_t)e * (H_DIM * D_DIM)) : Ws;
  const int n0 = blockIdx.y * 128;

  __shared__ bf16 As[128 * 32];
  __shared__ bf16 Bs[128 * 32];

  const int tid = threadIdx.x;
  const int wave = tid >> 6, lane = tid & 63;

  const int rS = tid >> 2;
  const int kc = (tid & 3) * 8;
  const bf16* gA0;
  const bf16* gA1;
  if (MODE == 0) {
    gA0 = Ab + (size_t)tok[base + rS] * 1024 + kc;
    gA1 = Ab + (size_t)tok[base + rS + 64] * 1024 + kc;
  } else {
    gA0 = Ab + (size_t)(base + rS) * 1024 + kc;
    gA1 = gA0 + (size_t)64 * 1024;
  }
  const bf16* gB0 = Bp + (size_t)(n0 + rS) * 1024 + kc;
  const bf16* gB1 = gB0 + (size_t)64 * 1024;
  bf16* sA0 = As + tid * 8;
  bf16* sA1 = As + 2048 + tid * 8;
  bf16* sB0 = Bs + tid * 8;
  bf16* sB1 = Bs + 2048 + tid * 8;

  const int wm = (wave >> 1) * 64, wn = (wave & 1) * 64;
  const int fr = lane & 15, q8 = (lane >> 4) * 8;
  const bf16* aP[4];
  const bf16* bP[4];
#pragma unroll
  for (int i = 0; i < 4; i++) {
    aP[i] = As + (wm + i * 16 + fr) * 32 + q8;
    bP[i] = Bs + (wn + i * 16 + fr) * 32 + q8;
  }

  const f32x4 zero = {0.f, 0.f, 0.f, 0.f};
  f32x4 acc[4][4];
#pragma unroll
  for (int i = 0; i < 4; i++)
#pragma unroll
    for (int j = 0; j < 4; j++) acc[i][j] = zero;

  for (int kt = 0; kt < 32; ++kt) {
    const int ko = kt * 32;
    async_ld16(gA0 + ko, sA0);
    async_ld16(gA1 + ko, sA1);
    async_ld16(gB0 + ko, sB0);
    async_ld16(gB1 + ko, sB1);
    __syncthreads();
    bf16x8 af[4], bfv[4];
#pragma unroll
    for (int i = 0; i < 4; i++) af[i] = *(const bf16x8*)aP[i];
#pragma unroll
    for (int j = 0; j < 4; j++) bfv[j] = *(const bf16x8*)bP[j];
#pragma unroll
    for (int i = 0; i < 4; i++)
#pragma unroll
      for (int j = 0; j < 4; j++)
        acc[i][j] = __builtin_amdgcn_mfma_f32_16x16x32_bf16(af[i], bfv[j],
                                                            acc[i][j], 0, 0, 0);
    __syncthreads();
  }

  const int rbase = (lane >> 4) * 4;
  if (MODE == 0) {
#pragma unroll
    for (int i = 0; i < 4; i++) {
#pragma unroll
      for (int j = 0; j < 4; j++) {
        const int col = n0 + wn + j * 16 + fr;
#pragma unroll
        for (int r = 0; r < 4; r++) {
          const int row = wm + i * 16 + rbase + r;
          float v = acc[i][j][r];
          v = v > 0.f ? v * v : 0.f;
          hid[(size_t)(base + row) * 1024 + col] = (bf16)v;
        }
      }
    }
  } else {
    const int valid = tV[mslot];
#pragma unroll
    for (int i = 0; i < 4; i++) {
#pragma unroll
      for (int r = 0; r < 4; r++) {
        const int row = wm + i * 16 + rbase + r;
        if (row < valid) {
          const int t = tok[base + row];
          const float wg = wgts[base + row];
          float* orow = out + (size_t)t * 1024 + n0 + wn + fr;
#pragma unroll
          for (int j = 0; j < 4; j++)
            atomicAdd(orow + j * 16, wg * acc[i][j][r]);
        }
      }
    }
  }
}

extern "C" void kernel_launch(void* const* d_in, const int* in_sizes, int n_in,
                              void* d_out, int out_size, void* d_ws,
                              size_t ws_size, hipStream_t stream) {
  const float* x     = (const float*)d_in[0];
  const float* gw    = (const float*)d_in[1];
  const float* lb    = (const float*)d_in[2];
  const float* w1    = (const float*)d_in[3];
  const float* w2    = (const float*)d_in[4];
  const float* cfc   = (const float*)d_in[5];
  const float* cproj = (const float*)d_in[6];
  float* out = (float*)d_out;
  char* ws = (char*)d_ws;

  int*   ntl   = (int*)(ws + WS_NTILES);
  int*   tE    = (int*)(ws + WS_TILE_E);
  int*   tB    = (int*)(ws + WS_TILE_BASE);
  int*   tV    = (int*)(ws + WS_TILE_VALID);
  int*   eidx  = (int*)(ws + WS_EIDX);
  float* wtok  = (float*)(ws + WS_WTOK);
  int*   tok   = (int*)(ws + WS_TOK);
  float* wgts  = (float*)(ws + WS_WGTS);
  bf16*  xg    = (bf16*)(ws + WS_XG);
  bf16*  hid   = (bf16*)(ws + WS_HID);
  bf16*  w1b   = (bf16*)(ws + WS_W1B);
  bf16*  w2b   = (bf16*)(ws + WS_W2B);
  bf16*  cfcb  = (bf16*)(ws + WS_CFCB);
  bf16*  cprojb= (bf16*)(ws + WS_CPROJB);

  hipMemsetAsync(out, 0, (size_t)out_size * sizeof(float), stream);

  convf2b<<<4096, 256, 0, stream>>>(w1, w1b, NE * H_DIM * D_DIM);
  convf2b<<<4096, 256, 0, stream>>>(w2, w2b, NE * D_DIM * H_DIM);
  convf2b<<<512, 256, 0, stream>>>(cfc, cfcb, H_DIM * D_DIM);
  convf2b<<<512, 256, 0, stream>>>(cproj, cprojb, D_DIM * H_DIM);

  router_kernel<<<NTOK / 4, 256, 0, stream>>>(x, gw, lb, eidx, wtok, xg);
  assign_kernel<<<1, 256, 0, stream>>>(eidx, wtok, tE, tB, tV, ntl, tok, wgts);

  moe_gemm<0><<<dim3(MAX_MSLOTS, 8), 256, 0, stream>>>(
      xg, w1b, cfcb, tE, tB, tV, ntl, hid, nullptr, tok, nullptr);
  moe_gemm<1><<<dim3(MAX_MSLOTS, 8), 256, 0, stream>>>(
      hid, w2b, cprojb, tE, tB, tV, ntl, nullptr, out, tok, wgts);
}